// Round 2
// baseline (743.236 us; speedup 1.0000x reference)
//
#include <hip/hip_runtime.h>
#include <hip/hip_bf16.h>

// ============================================================================
// SphCrossAttFusionBlock: B=8, DIM=256, Y=4096, H=8, D=64, INNER=512, w=256
// fp32 I/O; bf16 internal (ws) with fp32 MFMA accumulation.
// Pipeline: pack -> qproj -> kvproj -> attn -> outproj(+residual mix)
// ws layout (u16 elems):
//   xpT[s]: s*8388608                 [b][w=256][k=4096] (k = n*16+p*4+q)
//   q[s]:   16777216 + s*16777216     [b][o=512][y=4096] (o = h*64+d)
//   att[s]: 50331648 + s*16777216     [b][y=4096][c=512] (c = h*64+d)
//   k[s]:   83886080 + s*1048576      [b][h][j=256][d=64]
//   v[s]:   85983232 + s*1048576      [b][h][d=64][j=256]  (transposed)
// total 88080384 u16 = 176,160,768 bytes of d_ws
// ============================================================================

typedef unsigned short u16;
typedef unsigned int   u32;
typedef __bf16 v8bf __attribute__((ext_vector_type(8)));
typedef float  v4f  __attribute__((ext_vector_type(4)));
typedef u16    v8u  __attribute__((ext_vector_type(8)));

#define MFMA16(a,b,c) __builtin_amdgcn_mfma_f32_16x16x32_bf16((a),(b),(c),0,0,0)

__device__ __forceinline__ u16 f2bf(float f){ union{float f; u32 i;} x; x.f=f; u32 r=x.i+0x7FFFu+((x.i>>16)&1u); return (u16)(r>>16); }

__device__ __forceinline__ v8bf load8f_bf(const float* __restrict__ p){
  union { v8bf v; u16 u[8]; } t;
  float4 a = *(const float4*)p, b = *(const float4*)(p+4);
  t.u[0]=f2bf(a.x); t.u[1]=f2bf(a.y); t.u[2]=f2bf(a.z); t.u[3]=f2bf(a.w);
  t.u[4]=f2bf(b.x); t.u[5]=f2bf(b.y); t.u[6]=f2bf(b.z); t.u[7]=f2bf(b.w);
  return t.v;
}

#define OFF_XPT(s) ((size_t)(s)*8388608u)
#define OFF_Q(s)   ((size_t)16777216u + (size_t)(s)*16777216u)
#define OFF_ATT(s) ((size_t)50331648u + (size_t)(s)*16777216u)
#define OFF_K(s)   ((size_t)83886080u + (size_t)(s)*1048576u)
#define OFF_V(s)   ((size_t)85983232u + (size_t)(s)*1048576u)

// LDS xor-swizzle: byte offset within a row ^= (row&7)<<4. Same formula on
// write and read; 16B granule stays contiguous.

// ---------------------------------------------------------------------------
// pack: xpT[s][b][w][n*16+j] = bf16(x_s[b][n][w*16+j])
// block = (s,b,w); thread t handles n=t: read 16 fp32 (one 64B line), write
// 32B bf16 contiguous across threads.
// ---------------------------------------------------------------------------
__global__ __launch_bounds__(256) void pack_kernel(const float* __restrict__ x0,
    const float* __restrict__ x1, u16* __restrict__ ws) {
  const int w = blockIdx.x & 255;
  const int b = (blockIdx.x >> 8) & 7;
  const int s = blockIdx.x >> 11;
  const float* x = s ? x1 : x0;
  const int n = threadIdx.x;
  const float* src = x + ((size_t)(b*256 + n))*4096 + w*16;
  u16* dst = ws + OFF_XPT(s) + ((size_t)(b*256 + w))*4096 + n*16;
  float4 f0 = *(const float4*)(src);
  float4 f1 = *(const float4*)(src+4);
  float4 f2 = *(const float4*)(src+8);
  float4 f3 = *(const float4*)(src+12);
  union { v8u v; u16 u[8]; } lo, hi;
  lo.u[0]=f2bf(f0.x); lo.u[1]=f2bf(f0.y); lo.u[2]=f2bf(f0.z); lo.u[3]=f2bf(f0.w);
  lo.u[4]=f2bf(f1.x); lo.u[5]=f2bf(f1.y); lo.u[6]=f2bf(f1.z); lo.u[7]=f2bf(f1.w);
  hi.u[0]=f2bf(f2.x); hi.u[1]=f2bf(f2.y); hi.u[2]=f2bf(f2.z); hi.u[3]=f2bf(f2.w);
  hi.u[4]=f2bf(f3.x); hi.u[5]=f2bf(f3.y); hi.u[6]=f2bf(f3.z); hi.u[7]=f2bf(f3.w);
  *(v8u*)(dst)   = lo.v;
  *(v8u*)(dst+8) = hi.v;
}

// ---------------------------------------------------------------------------
// qproj: per (s,b): C[512,4096] = Wq[512,256] x x_b[256,4096] -> q[b][o][y]
// tile 128(o) x 128(y), 4 waves (2x2), each wave 4x4 16x16 frags, K=256
// ---------------------------------------------------------------------------
__global__ __launch_bounds__(256) void qproj_kernel(const float* __restrict__ x0,
    const float* __restrict__ x1, const float* __restrict__ Wq0,
    const float* __restrict__ Wq1, u16* __restrict__ ws) {
  const int yt = blockIdx.x;            // 0..31
  const int ot = blockIdx.y;            // 0..3
  const int s  = blockIdx.z >> 3, b = blockIdx.z & 7;
  const float* x  = s ? x1 : x0;
  const float* Wq = s ? Wq1 : Wq0;
  u16* qout = ws + OFF_Q(s);
  const int y0 = yt*128, o0 = ot*128;

  __shared__ u16 sm[32768];             // xT panel [128 y][256 n] swizzled (64KB)
  {
    const int tn = threadIdx.x >> 4;          // 0..15
    const int ty = (threadIdx.x & 15) * 8;    // 0..120 (ty&7==0)
    #pragma unroll
    for (int pass = 0; pass < 16; ++pass) {
      int n = pass*16 + tn;
      const float* src = x + ((size_t)(b*256 + n))*4096 + y0 + ty;
      float4 fa = *(const float4*)src, fb = *(const float4*)(src+4);
      u16 vals[8] = { f2bf(fa.x), f2bf(fa.y), f2bf(fa.z), f2bf(fa.w),
                      f2bf(fb.x), f2bf(fb.y), f2bf(fb.z), f2bf(fb.w) };
      #pragma unroll
      for (int j = 0; j < 8; ++j) {
        int row = ty + j;                     // row&7 == j
        int byte = row*512 + ((2*n) ^ (j<<4));
        sm[byte>>1] = vals[j];
      }
    }
  }
  __syncthreads();

  const int lane = threadIdx.x & 63, wv = threadIdx.x >> 6;
  const int l16 = lane & 15, g = lane >> 4;
  const int wm = wv >> 1, wn = wv & 1;

  v4f acc[4][4] = {};
  #pragma unroll
  for (int ks = 0; ks < 8; ++ks) {
    v8bf a[4], bb[4];
    #pragma unroll
    for (int mt = 0; mt < 4; ++mt)
      a[mt] = load8f_bf(Wq + (size_t)(o0 + wm*64 + mt*16 + l16)*256 + ks*32 + g*8);
    #pragma unroll
    for (int nt = 0; nt < 4; ++nt) {
      int row = wn*64 + nt*16 + l16;
      int c = ks*4 + g;
      int byte = row*512 + ((c*16) ^ ((row&7)<<4));
      bb[nt] = *(const v8bf*)&sm[byte>>1];
    }
    #pragma unroll
    for (int mt = 0; mt < 4; ++mt)
      #pragma unroll
      for (int nt = 0; nt < 4; ++nt)
        acc[mt][nt] = MFMA16(a[mt], bb[nt], acc[mt][nt]);
  }
  #pragma unroll
  for (int mt = 0; mt < 4; ++mt)
    #pragma unroll
    for (int nt = 0; nt < 4; ++nt)
      #pragma unroll
      for (int r = 0; r < 4; ++r) {
        int o = o0 + wm*64 + mt*16 + g*4 + r;
        int y = y0 + wn*64 + nt*16 + l16;
        qout[(size_t)(b*512 + o)*4096 + y] = f2bf(acc[mt][nt][r]);
      }
}

// ---------------------------------------------------------------------------
// kvproj: per (s,b): C[1024,256] = Wkv[1024,4096] x xpT_b^T, K chunked by 64.
// o<512 -> k[b][h][w][d]; o>=512 -> v[b][h][d][w] (transposed store)
// ---------------------------------------------------------------------------
__global__ __launch_bounds__(256) void kvproj_kernel(const float* __restrict__ Wkv0,
    const float* __restrict__ Wkv1, u16* __restrict__ ws) {
  const int wt = blockIdx.x;            // 0..1
  const int ot = blockIdx.y;            // 0..7
  const int s  = blockIdx.z >> 3, b = blockIdx.z & 7;
  const float* Wkv = s ? Wkv1 : Wkv0;
  const u16* xpT = ws + OFF_XPT(s);
  const int w0 = wt*128, o0 = ot*128;

  __shared__ u16 sm[8192];              // B panel [128 w][64 k] swizzled (16KB)
  const int lane = threadIdx.x & 63, wvv = threadIdx.x >> 6;
  const int l16 = lane & 15, g = lane >> 4;
  const int wm = wvv >> 1, wn = wvv & 1;

  v4f acc[4][4] = {};
  for (int kc = 0; kc < 64; ++kc) {
    __syncthreads();
    #pragma unroll
    for (int pass = 0; pass < 4; ++pass) {
      int idx = pass*256 + threadIdx.x;
      int row = idx >> 3, u = idx & 7;
      v8u val = *(const v8u*)(xpT + (size_t)(b*256 + w0 + row)*4096 + kc*64 + u*8);
      int byte = row*128 + ((u*16) ^ ((row&7)<<4));
      *(v8u*)&sm[byte>>1] = val;
    }
    __syncthreads();
    #pragma unroll
    for (int ks = 0; ks < 2; ++ks) {
      v8bf a[4], bb[4];
      #pragma unroll
      for (int mt = 0; mt < 4; ++mt)
        a[mt] = load8f_bf(Wkv + (size_t)(o0 + wm*64 + mt*16 + l16)*4096 + kc*64 + ks*32 + g*8);
      #pragma unroll
      for (int nt = 0; nt < 4; ++nt) {
        int row = wn*64 + nt*16 + l16;
        int c = ks*4 + g;
        int byte = row*128 + ((c*16) ^ ((row&7)<<4));
        bb[nt] = *(const v8bf*)&sm[byte>>1];
      }
      #pragma unroll
      for (int mt = 0; mt < 4; ++mt)
        #pragma unroll
        for (int nt = 0; nt < 4; ++nt)
          acc[mt][nt] = MFMA16(a[mt], bb[nt], acc[mt][nt]);
    }
  }
  u16* kout = ws + OFF_K(s);
  u16* vout = ws + OFF_V(s);
  #pragma unroll
  for (int mt = 0; mt < 4; ++mt)
    #pragma unroll
    for (int nt = 0; nt < 4; ++nt)
      #pragma unroll
      for (int r = 0; r < 4; ++r) {
        int o = o0 + wm*64 + mt*16 + g*4 + r;
        int w = w0 + wn*64 + nt*16 + l16;
        u16 val = f2bf(acc[mt][nt][r]);
        if (o < 512) { int hh = o>>6, d = o&63; kout[((size_t)(b*8+hh)*256 + w)*64 + d] = val; }
        else { int oo = o-512; int hh = oo>>6, d = oo&63; vout[((size_t)(b*8+hh)*64 + d)*256 + w] = val; }
      }
}

// ---------------------------------------------------------------------------
// attn: per (s,b,h,itile): 64 q-rows (16/wave). Stream s uses q_s, k/v_{1-s}.
// LDS: bytes [0,32768): K [256 j][64 d] (reused for P after barrier)
//      bytes [32768,65536): Vt [64 d][256 j]
// ---------------------------------------------------------------------------
__global__ __launch_bounds__(256) void attn_kernel(u16* __restrict__ ws) {
  const int it = blockIdx.x;            // 0..63
  const int hh = blockIdx.y;            // 0..7
  const int s  = blockIdx.z >> 3, b = blockIdx.z & 7;
  const u16* q  = ws + OFF_Q(s);
  const u16* kk = ws + OFF_K(1-s);
  const u16* vv = ws + OFF_V(1-s);
  u16* att = ws + OFF_ATT(s);

  __shared__ u16 sm[32768];             // 64KB
  const int lane = threadIdx.x & 63, wv = threadIdx.x >> 6;
  const int l16 = lane & 15, g = lane >> 4;

  const u16* kbase = kk + (size_t)(b*8+hh)*16384;
  #pragma unroll
  for (int pass = 0; pass < 8; ++pass) {
    int byte = pass*4096 + threadIdx.x*16;
    int row = byte >> 7, u = (byte >> 4) & 7;
    v8u val = *(const v8u*)(kbase + row*64 + u*8);
    int db = row*128 + ((u*16) ^ ((row&7)<<4));
    *(v8u*)&sm[db>>1] = val;
  }
  const u16* vbase = vv + (size_t)(b*8+hh)*16384;
  #pragma unroll
  for (int pass = 0; pass < 8; ++pass) {
    int byte = pass*4096 + threadIdx.x*16;
    int row = byte >> 9, u = (byte >> 4) & 31;
    v8u val = *(const v8u*)(vbase + row*256 + u*8);
    int db = 32768 + row*512 + ((u*16) ^ ((row&7)<<4));
    *(v8u*)&sm[db>>1] = val;
  }
  __syncthreads();

  const int i0 = it*64 + wv*16;
  v8bf aq[2];
  {
    union { v8bf v; u16 u[8]; } tmp;
    #pragma unroll
    for (int half = 0; half < 2; ++half) {
      #pragma unroll
      for (int jj = 0; jj < 8; ++jj) {
        int d = half*32 + g*8 + jj;
        tmp.u[jj] = q[((size_t)(b*512) + hh*64 + d)*4096 + i0 + l16];
      }
      aq[half] = tmp.v;
    }
  }
  // QK^T: S[16 i][256 j] in 16 frags
  v4f sfr[16];
  #pragma unroll
  for (int t = 0; t < 16; ++t) {
    v4f acc = {};
    #pragma unroll
    for (int half = 0; half < 2; ++half) {
      int row = t*16 + l16;
      int c = half*4 + g;
      int byte = row*128 + ((c*16) ^ ((row&7)<<4));
      v8bf bk = *(const v8bf*)&sm[byte>>1];
      acc = MFMA16(aq[half], bk, acc);
    }
    sfr[t] = acc;
  }
  // softmax over j (scale 1/8); rows i_local = g*4 + r live on 16-lane group g
  float inv4[4];
  #pragma unroll
  for (int r = 0; r < 4; ++r) {
    float m = -3.0e38f;
    #pragma unroll
    for (int t = 0; t < 16; ++t) m = fmaxf(m, sfr[t][r]);
    #pragma unroll
    for (int off = 1; off < 16; off <<= 1) m = fmaxf(m, __shfl_xor(m, off));
    float sum = 0.f;
    #pragma unroll
    for (int t = 0; t < 16; ++t) {
      float p = exp2f((sfr[t][r] - m) * 0.18033688011112042f);  // (1/8)*log2(e)
      sfr[t][r] = p;
      sum += p;
    }
    #pragma unroll
    for (int off = 1; off < 16; off <<= 1) sum += __shfl_xor(sum, off);
    inv4[r] = 1.0f / sum;
  }
  __syncthreads();                      // all waves done reading K region
  // P -> LDS (per-wave 8KB slice of former K region), layout [16 i][256 j]
  const int pbase = wv*8192;
  #pragma unroll
  for (int t = 0; t < 16; ++t)
    #pragma unroll
    for (int r = 0; r < 4; ++r) {
      int irow = g*4 + r;
      int j = t*16 + l16;
      int byte = pbase + irow*512 + ((2*j) ^ ((irow&7)<<4));
      sm[byte>>1] = f2bf(sfr[t][r] * inv4[r]);
    }
  __syncthreads();                      // P visible / ordered before PV reads
  // PV: O[16 i][64 d]
  v4f oacc[4] = {};
  #pragma unroll
  for (int ksj = 0; ksj < 8; ++ksj) {
    int cp = ksj*4 + g;
    int pbyte = pbase + l16*512 + ((cp*16) ^ ((l16&7)<<4));
    v8bf pa = *(const v8bf*)&sm[pbyte>>1];
    #pragma unroll
    for (int dt = 0; dt < 4; ++dt) {
      int rowv = dt*16 + l16;
      int byte = 32768 + rowv*512 + ((cp*16) ^ ((rowv&7)<<4));
      v8bf vb = *(const v8bf*)&sm[byte>>1];
      oacc[dt] = MFMA16(pa, vb, oacc[dt]);
    }
  }
  #pragma unroll
  for (int dt = 0; dt < 4; ++dt)
    #pragma unroll
    for (int r = 0; r < 4; ++r) {
      int i = i0 + g*4 + r;
      int c = hh*64 + dt*16 + l16;
      att[((size_t)(b*4096) + i)*512 + c] = f2bf(oacc[dt][r]);
    }
}

// ---------------------------------------------------------------------------
// outproj: out[b][o][y] = 0.5*(x0+x1 + bout0[o]+bout1[o]
//                              + Wout0@att0 + Wout1@att1)   (fp32 out)
// tile 128(o) x 128(y); B-frags straight from global att[b][y][c]
// ---------------------------------------------------------------------------
__global__ __launch_bounds__(256) void outproj_kernel(const float* __restrict__ x0,
    const float* __restrict__ x1, const float* __restrict__ Wout0,
    const float* __restrict__ Wout1, const float* __restrict__ bout0,
    const float* __restrict__ bout1, const u16* __restrict__ ws,
    float* __restrict__ out) {
  const int yt = blockIdx.x;            // 0..31
  const int ot = blockIdx.y;            // 0..1
  const int b  = blockIdx.z;            // 0..7
  const int lane = threadIdx.x & 63, wv = threadIdx.x >> 6;
  const int l16 = lane & 15, g = lane >> 4;
  const int wm = wv >> 1, wn = wv & 1;
  const int y0 = yt*128, o0 = ot*128;

  v4f acc[4][4] = {};
  #pragma unroll
  for (int s = 0; s < 2; ++s) {
    const float* Wout = s ? Wout1 : Wout0;
    const u16* att = ws + OFF_ATT(s);
    #pragma unroll
    for (int ks = 0; ks < 16; ++ks) {
      v8bf a[4], bb[4];
      #pragma unroll
      for (int mt = 0; mt < 4; ++mt)
        a[mt] = load8f_bf(Wout + (size_t)(o0 + wm*64 + mt*16 + l16)*512 + ks*32 + g*8);
      #pragma unroll
      for (int nt = 0; nt < 4; ++nt)
        bb[nt] = *(const v8bf*)(att + ((size_t)(b*4096) + y0 + wn*64 + nt*16 + l16)*512 + ks*32 + g*8);
      #pragma unroll
      for (int mt = 0; mt < 4; ++mt)
        #pragma unroll
        for (int nt = 0; nt < 4; ++nt)
          acc[mt][nt] = MFMA16(a[mt], bb[nt], acc[mt][nt]);
    }
  }
  #pragma unroll
  for (int mt = 0; mt < 4; ++mt)
    #pragma unroll
    for (int nt = 0; nt < 4; ++nt)
      #pragma unroll
      for (int r = 0; r < 4; ++r) {
        int o = o0 + wm*64 + mt*16 + g*4 + r;
        int y = y0 + wn*64 + nt*16 + l16;
        size_t idx = (size_t)(b*256 + o)*4096 + y;
        float bias = bout0[o] + bout1[o];
        out[idx] = 0.5f*(acc[mt][nt][r] + bias + x0[idx] + x1[idx]);
      }
}

// ---------------------------------------------------------------------------
extern "C" void kernel_launch(void* const* d_in, const int* in_sizes, int n_in,
                              void* d_out, int out_size, void* d_ws, size_t ws_size,
                              hipStream_t stream) {
  const float* x0    = (const float*)d_in[0];
  const float* x1    = (const float*)d_in[1];
  const float* Wq0   = (const float*)d_in[2];
  const float* Wkv0  = (const float*)d_in[3];
  const float* Wq1   = (const float*)d_in[4];
  const float* Wkv1  = (const float*)d_in[5];
  const float* Wout0 = (const float*)d_in[6];
  const float* bout0 = (const float*)d_in[7];
  const float* Wout1 = (const float*)d_in[8];
  const float* bout1 = (const float*)d_in[9];
  u16*   ws  = (u16*)d_ws;
  float* out = (float*)d_out;

  pack_kernel   <<<4096, 256, 0, stream>>>(x0, x1, ws);
  qproj_kernel  <<<dim3(32,4,16), 256, 0, stream>>>(x0, x1, Wq0, Wq1, ws);
  kvproj_kernel <<<dim3(2,8,16),  256, 0, stream>>>(Wkv0, Wkv1, ws);
  attn_kernel   <<<dim3(64,8,16), 256, 0, stream>>>(ws);
  outproj_kernel<<<dim3(32,2,8),  256, 0, stream>>>(x0, x1, Wout0, Wout1,
                                                    bout0, bout1, ws, out);
}

// Round 3
// 729.980 us; speedup vs baseline: 1.0182x; 1.0182x over previous
//
#include <hip/hip_runtime.h>
#include <hip/hip_bf16.h>

// ============================================================================
// SphCrossAttFusionBlock: B=8, DIM=256, Y=4096, H=8, D=64, INNER=512, w=256
// fp32 I/O; bf16 internal (ws) with fp32 MFMA accumulation.
// Pipeline: pack -> wconv -> qproj -> kvproj -> attn -> outproj(+residual)
// ws layout (u16 elems):
//   xpT[s]: s*8388608                 [b][w=256][k=4096] (k = n*16+p*4+q)
//   q[s]:   16777216 + s*16777216     [b][o=512][y=4096] (o = h*64+d)
//   att[s]: 50331648 + s*16777216     [b][y=4096][c=512] (c = h*64+d)
//     NOTE: first 8388608 u16 of the att0 region double as wkv_bf[2][1024][4096]
//     (written by wconv, consumed by kvproj, then overwritten by attn).
//   k[s]:   83886080 + s*1048576      [b][h][j=256][d=64]
//   v[s]:   85983232 + s*1048576      [b][h][d=64][j=256]  (transposed)
// total 88080384 u16 = 176,160,768 bytes of d_ws (unchanged from round 2)
// ============================================================================

typedef unsigned short u16;
typedef unsigned int   u32;
typedef __bf16 v8bf __attribute__((ext_vector_type(8)));
typedef float  v4f  __attribute__((ext_vector_type(4)));
typedef u16    v8u  __attribute__((ext_vector_type(8)));

#define MFMA16(a,b,c) __builtin_amdgcn_mfma_f32_16x16x32_bf16((a),(b),(c),0,0,0)

__device__ __forceinline__ u16 f2bf(float f){ union{float f; u32 i;} x; x.f=f; u32 r=x.i+0x7FFFu+((x.i>>16)&1u); return (u16)(r>>16); }

__device__ __forceinline__ v8bf load8f_bf(const float* __restrict__ p){
  union { v8bf v; u16 u[8]; } t;
  float4 a = *(const float4*)p, b = *(const float4*)(p+4);
  t.u[0]=f2bf(a.x); t.u[1]=f2bf(a.y); t.u[2]=f2bf(a.z); t.u[3]=f2bf(a.w);
  t.u[4]=f2bf(b.x); t.u[5]=f2bf(b.y); t.u[6]=f2bf(b.z); t.u[7]=f2bf(b.w);
  return t.v;
}

#define OFF_XPT(s) ((size_t)(s)*8388608u)
#define OFF_Q(s)   ((size_t)16777216u + (size_t)(s)*16777216u)
#define OFF_ATT(s) ((size_t)50331648u + (size_t)(s)*16777216u)
#define OFF_WKV(s) ((size_t)50331648u + (size_t)(s)*4194304u)   // aliases att0 head
#define OFF_K(s)   ((size_t)83886080u + (size_t)(s)*1048576u)
#define OFF_V(s)   ((size_t)85983232u + (size_t)(s)*1048576u)

// LDS xor-swizzle: byte offset within a row ^= (row&7)<<4. Same formula on
// write and read; 16B granule stays contiguous.

// ---------------------------------------------------------------------------
// pack: xpT[s][b][w][n*16+j] = bf16(x_s[b][n][w*16+j])
// ---------------------------------------------------------------------------
__global__ __launch_bounds__(256) void pack_kernel(const float* __restrict__ x0,
    const float* __restrict__ x1, u16* __restrict__ ws) {
  const int w = blockIdx.x & 255;
  const int b = (blockIdx.x >> 8) & 7;
  const int s = blockIdx.x >> 11;
  const float* x = s ? x1 : x0;
  const int n = threadIdx.x;
  const float* src = x + ((size_t)(b*256 + n))*4096 + w*16;
  u16* dst = ws + OFF_XPT(s) + ((size_t)(b*256 + w))*4096 + n*16;
  float4 f0 = *(const float4*)(src);
  float4 f1 = *(const float4*)(src+4);
  float4 f2 = *(const float4*)(src+8);
  float4 f3 = *(const float4*)(src+12);
  union { v8u v; u16 u[8]; } lo, hi;
  lo.u[0]=f2bf(f0.x); lo.u[1]=f2bf(f0.y); lo.u[2]=f2bf(f0.z); lo.u[3]=f2bf(f0.w);
  lo.u[4]=f2bf(f1.x); lo.u[5]=f2bf(f1.y); lo.u[6]=f2bf(f1.z); lo.u[7]=f2bf(f1.w);
  hi.u[0]=f2bf(f2.x); hi.u[1]=f2bf(f2.y); hi.u[2]=f2bf(f2.z); hi.u[3]=f2bf(f2.w);
  hi.u[4]=f2bf(f3.x); hi.u[5]=f2bf(f3.y); hi.u[6]=f2bf(f3.z); hi.u[7]=f2bf(f3.w);
  *(v8u*)(dst)   = lo.v;
  *(v8u*)(dst+8) = hi.v;
}

// ---------------------------------------------------------------------------
// wconv: wkv_bf[s][o][k] = bf16(Wkv_s[o][k])  (16.8 MB total, one-shot)
// ---------------------------------------------------------------------------
__global__ __launch_bounds__(256) void wconv_kernel(const float* __restrict__ Wkv0,
    const float* __restrict__ Wkv1, u16* __restrict__ ws) {
  int tid = blockIdx.x*256 + threadIdx.x;       // 1,048,576 threads
  int s = tid >> 19;                            // 524288 threads per stream
  int i8 = tid & 524287;
  const float* W = s ? Wkv1 : Wkv0;
  const float* src = W + (size_t)i8*8;
  u16* dst = ws + OFF_WKV(s) + (size_t)i8*8;
  float4 a = *(const float4*)src, b = *(const float4*)(src+4);
  union { v8u v; u16 u[8]; } t;
  t.u[0]=f2bf(a.x); t.u[1]=f2bf(a.y); t.u[2]=f2bf(a.z); t.u[3]=f2bf(a.w);
  t.u[4]=f2bf(b.x); t.u[5]=f2bf(b.y); t.u[6]=f2bf(b.z); t.u[7]=f2bf(b.w);
  *(v8u*)dst = t.v;
}

// ---------------------------------------------------------------------------
// qproj: per (s,b): C[512,4096] = Wq[512,256] x x_b[256,4096] -> q[b][o][y]
// tile 128(o) x 128(y), 4 waves (2x2), each wave 4x4 16x16 frags, K=256
// ---------------------------------------------------------------------------
__global__ __launch_bounds__(256) void qproj_kernel(const float* __restrict__ x0,
    const float* __restrict__ x1, const float* __restrict__ Wq0,
    const float* __restrict__ Wq1, u16* __restrict__ ws) {
  const int yt = blockIdx.x;            // 0..31
  const int ot = blockIdx.y;            // 0..3
  const int s  = blockIdx.z >> 3, b = blockIdx.z & 7;
  const float* x  = s ? x1 : x0;
  const float* Wq = s ? Wq1 : Wq0;
  u16* qout = ws + OFF_Q(s);
  const int y0 = yt*128, o0 = ot*128;

  __shared__ u16 sm[32768];             // xT panel [128 y][256 n] swizzled (64KB)
  {
    const int tn = threadIdx.x >> 4;          // 0..15
    const int ty = (threadIdx.x & 15) * 8;    // 0..120 (ty&7==0)
    #pragma unroll
    for (int pass = 0; pass < 16; ++pass) {
      int n = pass*16 + tn;
      const float* src = x + ((size_t)(b*256 + n))*4096 + y0 + ty;
      float4 fa = *(const float4*)src, fb = *(const float4*)(src+4);
      u16 vals[8] = { f2bf(fa.x), f2bf(fa.y), f2bf(fa.z), f2bf(fa.w),
                      f2bf(fb.x), f2bf(fb.y), f2bf(fb.z), f2bf(fb.w) };
      #pragma unroll
      for (int j = 0; j < 8; ++j) {
        int row = ty + j;                     // row&7 == j
        int byte = row*512 + ((2*n) ^ (j<<4));
        sm[byte>>1] = vals[j];
      }
    }
  }
  __syncthreads();

  const int lane = threadIdx.x & 63, wv = threadIdx.x >> 6;
  const int l16 = lane & 15, g = lane >> 4;
  const int wm = wv >> 1, wn = wv & 1;

  v4f acc[4][4] = {};
  #pragma unroll
  for (int ks = 0; ks < 8; ++ks) {
    v8bf a[4], bb[4];
    #pragma unroll
    for (int mt = 0; mt < 4; ++mt)
      a[mt] = load8f_bf(Wq + (size_t)(o0 + wm*64 + mt*16 + l16)*256 + ks*32 + g*8);
    #pragma unroll
    for (int nt = 0; nt < 4; ++nt) {
      int row = wn*64 + nt*16 + l16;
      int c = ks*4 + g;
      int byte = row*512 + ((c*16) ^ ((row&7)<<4));
      bb[nt] = *(const v8bf*)&sm[byte>>1];
    }
    #pragma unroll
    for (int mt = 0; mt < 4; ++mt)
      #pragma unroll
      for (int nt = 0; nt < 4; ++nt)
        acc[mt][nt] = MFMA16(a[mt], bb[nt], acc[mt][nt]);
  }
  #pragma unroll
  for (int mt = 0; mt < 4; ++mt)
    #pragma unroll
    for (int nt = 0; nt < 4; ++nt)
      #pragma unroll
      for (int r = 0; r < 4; ++r) {
        int o = o0 + wm*64 + mt*16 + g*4 + r;
        int y = y0 + wn*64 + nt*16 + l16;
        qout[(size_t)(b*512 + o)*4096 + y] = f2bf(acc[mt][nt][r]);
      }
}

// ---------------------------------------------------------------------------
// kvproj v2: per (s,b): C[1024,256] = wkv_bf[1024,4096] x xpT_b^T
// No LDS, no barriers. 1024 blocks (ot=8 x wt=8 x sb=16), 4 waves/block,
// wave tile 32(o) x 32(w), direct bf16 global loads (A via L2: blockIdx.x=ot
// co-locates panel sharers on one XCD; B dedups in L1 across the block).
// o<512 -> k[b][h][w][d]; o>=512 -> v[b][h][d][w] (transposed store)
// ---------------------------------------------------------------------------
__global__ __launch_bounds__(256) void kvproj_kernel(u16* __restrict__ ws) {
  const int ot = blockIdx.x;            // 0..7  (XCD = bid%8 = ot)
  const int wt = blockIdx.y;            // 0..7
  const int s  = blockIdx.z >> 3, b = blockIdx.z & 7;
  const u16* W   = ws + OFF_WKV(s);
  const u16* xpT = ws + OFF_XPT(s);
  const int lane = threadIdx.x & 63, wv = threadIdx.x >> 6;
  const int l16 = lane & 15, g = lane >> 4;
  const int o0 = ot*128 + wv*32;
  const int w0 = wt*32;

  const u16* A0 = W + (size_t)(o0 + l16)*4096 + g*8;
  const u16* A1 = A0 + 16*4096;
  const u16* B0 = xpT + (size_t)(b*256 + w0 + l16)*4096 + g*8;
  const u16* B1 = B0 + 16*4096;

  v4f acc[2][2] = {};
  #pragma unroll 2
  for (int k0 = 0; k0 < 4096; k0 += 64) {
    v8bf a00 = *(const v8bf*)(A0 + k0);
    v8bf a01 = *(const v8bf*)(A0 + k0 + 32);
    v8bf a10 = *(const v8bf*)(A1 + k0);
    v8bf a11 = *(const v8bf*)(A1 + k0 + 32);
    v8bf b00 = *(const v8bf*)(B0 + k0);
    v8bf b01 = *(const v8bf*)(B0 + k0 + 32);
    v8bf b10 = *(const v8bf*)(B1 + k0);
    v8bf b11 = *(const v8bf*)(B1 + k0 + 32);
    acc[0][0] = MFMA16(a00, b00, acc[0][0]);
    acc[0][1] = MFMA16(a00, b10, acc[0][1]);
    acc[1][0] = MFMA16(a10, b00, acc[1][0]);
    acc[1][1] = MFMA16(a10, b10, acc[1][1]);
    acc[0][0] = MFMA16(a01, b01, acc[0][0]);
    acc[0][1] = MFMA16(a01, b11, acc[0][1]);
    acc[1][0] = MFMA16(a11, b01, acc[1][0]);
    acc[1][1] = MFMA16(a11, b11, acc[1][1]);
  }

  u16* kout = ws + OFF_K(s);
  u16* vout = ws + OFF_V(s);
  #pragma unroll
  for (int mt = 0; mt < 2; ++mt)
    #pragma unroll
    for (int nt = 0; nt < 2; ++nt)
      #pragma unroll
      for (int r = 0; r < 4; ++r) {
        int o = o0 + mt*16 + g*4 + r;
        int w = w0 + nt*16 + l16;
        u16 val = f2bf(acc[mt][nt][r]);
        if (o < 512) { int hh = o>>6, d = o&63; kout[((size_t)(b*8+hh)*256 + w)*64 + d] = val; }
        else { int oo = o-512; int hh = oo>>6, d = oo&63; vout[((size_t)(b*8+hh)*64 + d)*256 + w] = val; }
      }
}

// ---------------------------------------------------------------------------
// attn: per (s,b,h,itile): 64 q-rows (16/wave). Stream s uses q_s, k/v_{1-s}.
// LDS: bytes [0,32768): K [256 j][64 d] (reused for P after barrier)
//      bytes [32768,65536): Vt [64 d][256 j]
// ---------------------------------------------------------------------------
__global__ __launch_bounds__(256) void attn_kernel(u16* __restrict__ ws) {
  const int it = blockIdx.x;            // 0..63
  const int hh = blockIdx.y;            // 0..7
  const int s  = blockIdx.z >> 3, b = blockIdx.z & 7;
  const u16* q  = ws + OFF_Q(s);
  const u16* kk = ws + OFF_K(1-s);
  const u16* vv = ws + OFF_V(1-s);
  u16* att = ws + OFF_ATT(s);

  __shared__ u16 sm[32768];             // 64KB
  const int lane = threadIdx.x & 63, wv = threadIdx.x >> 6;
  const int l16 = lane & 15, g = lane >> 4;

  const u16* kbase = kk + (size_t)(b*8+hh)*16384;
  #pragma unroll
  for (int pass = 0; pass < 8; ++pass) {
    int byte = pass*4096 + threadIdx.x*16;
    int row = byte >> 7, u = (byte >> 4) & 7;
    v8u val = *(const v8u*)(kbase + row*64 + u*8);
    int db = row*128 + ((u*16) ^ ((row&7)<<4));
    *(v8u*)&sm[db>>1] = val;
  }
  const u16* vbase = vv + (size_t)(b*8+hh)*16384;
  #pragma unroll
  for (int pass = 0; pass < 8; ++pass) {
    int byte = pass*4096 + threadIdx.x*16;
    int row = byte >> 9, u = (byte >> 4) & 31;
    v8u val = *(const v8u*)(vbase + row*256 + u*8);
    int db = 32768 + row*512 + ((u*16) ^ ((row&7)<<4));
    *(v8u*)&sm[db>>1] = val;
  }
  __syncthreads();

  const int i0 = it*64 + wv*16;
  v8bf aq[2];
  {
    union { v8bf v; u16 u[8]; } tmp;
    #pragma unroll
    for (int half = 0; half < 2; ++half) {
      #pragma unroll
      for (int jj = 0; jj < 8; ++jj) {
        int d = half*32 + g*8 + jj;
        tmp.u[jj] = q[((size_t)(b*512) + hh*64 + d)*4096 + i0 + l16];
      }
      aq[half] = tmp.v;
    }
  }
  // QK^T: S[16 i][256 j] in 16 frags
  v4f sfr[16];
  #pragma unroll
  for (int t = 0; t < 16; ++t) {
    v4f acc = {};
    #pragma unroll
    for (int half = 0; half < 2; ++half) {
      int row = t*16 + l16;
      int c = half*4 + g;
      int byte = row*128 + ((c*16) ^ ((row&7)<<4));
      v8bf bk = *(const v8bf*)&sm[byte>>1];
      acc = MFMA16(aq[half], bk, acc);
    }
    sfr[t] = acc;
  }
  // softmax over j (scale 1/8); rows i_local = g*4 + r live on 16-lane group g
  float inv4[4];
  #pragma unroll
  for (int r = 0; r < 4; ++r) {
    float m = -3.0e38f;
    #pragma unroll
    for (int t = 0; t < 16; ++t) m = fmaxf(m, sfr[t][r]);
    #pragma unroll
    for (int off = 1; off < 16; off <<= 1) m = fmaxf(m, __shfl_xor(m, off));
    float sum = 0.f;
    #pragma unroll
    for (int t = 0; t < 16; ++t) {
      float p = exp2f((sfr[t][r] - m) * 0.18033688011112042f);  // (1/8)*log2(e)
      sfr[t][r] = p;
      sum += p;
    }
    #pragma unroll
    for (int off = 1; off < 16; off <<= 1) sum += __shfl_xor(sum, off);
    inv4[r] = 1.0f / sum;
  }
  __syncthreads();                      // all waves done reading K region
  // P -> LDS (per-wave 8KB slice of former K region), layout [16 i][256 j]
  const int pbase = wv*8192;
  #pragma unroll
  for (int t = 0; t < 16; ++t)
    #pragma unroll
    for (int r = 0; r < 4; ++r) {
      int irow = g*4 + r;
      int j = t*16 + l16;
      int byte = pbase + irow*512 + ((2*j) ^ ((irow&7)<<4));
      sm[byte>>1] = f2bf(sfr[t][r] * inv4[r]);
    }
  __syncthreads();                      // P visible / ordered before PV reads
  // PV: O[16 i][64 d]
  v4f oacc[4] = {};
  #pragma unroll
  for (int ksj = 0; ksj < 8; ++ksj) {
    int cp = ksj*4 + g;
    int pbyte = pbase + l16*512 + ((cp*16) ^ ((l16&7)<<4));
    v8bf pa = *(const v8bf*)&sm[pbyte>>1];
    #pragma unroll
    for (int dt = 0; dt < 4; ++dt) {
      int rowv = dt*16 + l16;
      int byte = 32768 + rowv*512 + ((cp*16) ^ ((rowv&7)<<4));
      v8bf vb = *(const v8bf*)&sm[byte>>1];
      oacc[dt] = MFMA16(pa, vb, oacc[dt]);
    }
  }
  #pragma unroll
  for (int dt = 0; dt < 4; ++dt)
    #pragma unroll
    for (int r = 0; r < 4; ++r) {
      int i = i0 + g*4 + r;
      int c = hh*64 + dt*16 + l16;
      att[((size_t)(b*4096) + i)*512 + c] = f2bf(oacc[dt][r]);
    }
}

// ---------------------------------------------------------------------------
// outproj: out[b][o][y] = 0.5*(x0+x1 + bout0[o]+bout1[o]
//                              + Wout0@att0 + Wout1@att1)   (fp32 out)
// tile 128(o) x 128(y); B-frags straight from global att[b][y][c]
// ---------------------------------------------------------------------------
__global__ __launch_bounds__(256) void outproj_kernel(const float* __restrict__ x0,
    const float* __restrict__ x1, const float* __restrict__ Wout0,
    const float* __restrict__ Wout1, const float* __restrict__ bout0,
    const float* __restrict__ bout1, const u16* __restrict__ ws,
    float* __restrict__ out) {
  const int yt = blockIdx.x;            // 0..31
  const int ot = blockIdx.y;            // 0..1
  const int b  = blockIdx.z;            // 0..7
  const int lane = threadIdx.x & 63, wv = threadIdx.x >> 6;
  const int l16 = lane & 15, g = lane >> 4;
  const int wm = wv >> 1, wn = wv & 1;
  const int y0 = yt*128, o0 = ot*128;

  v4f acc[4][4] = {};
  #pragma unroll
  for (int s = 0; s < 2; ++s) {
    const float* Wout = s ? Wout1 : Wout0;
    const u16* att = ws + OFF_ATT(s);
    #pragma unroll
    for (int ks = 0; ks < 16; ++ks) {
      v8bf a[4], bb[4];
      #pragma unroll
      for (int mt = 0; mt < 4; ++mt)
        a[mt] = load8f_bf(Wout + (size_t)(o0 + wm*64 + mt*16 + l16)*512 + ks*32 + g*8);
      #pragma unroll
      for (int nt = 0; nt < 4; ++nt)
        bb[nt] = *(const v8bf*)(att + ((size_t)(b*4096) + y0 + wn*64 + nt*16 + l16)*512 + ks*32 + g*8);
      #pragma unroll
      for (int mt = 0; mt < 4; ++mt)
        #pragma unroll
        for (int nt = 0; nt < 4; ++nt)
          acc[mt][nt] = MFMA16(a[mt], bb[nt], acc[mt][nt]);
    }
  }
  #pragma unroll
  for (int mt = 0; mt < 4; ++mt)
    #pragma unroll
    for (int nt = 0; nt < 4; ++nt)
      #pragma unroll
      for (int r = 0; r < 4; ++r) {
        int o = o0 + wm*64 + mt*16 + g*4 + r;
        int y = y0 + wn*64 + nt*16 + l16;
        size_t idx = (size_t)(b*256 + o)*4096 + y;
        float bias = bout0[o] + bout1[o];
        out[idx] = 0.5f*(acc[mt][nt][r] + bias + x0[idx] + x1[idx]);
      }
}

// ---------------------------------------------------------------------------
extern "C" void kernel_launch(void* const* d_in, const int* in_sizes, int n_in,
                              void* d_out, int out_size, void* d_ws, size_t ws_size,
                              hipStream_t stream) {
  const float* x0    = (const float*)d_in[0];
  const float* x1    = (const float*)d_in[1];
  const float* Wq0   = (const float*)d_in[2];
  const float* Wkv0  = (const float*)d_in[3];
  const float* Wq1   = (const float*)d_in[4];
  const float* Wkv1  = (const float*)d_in[5];
  const float* Wout0 = (const float*)d_in[6];
  const float* bout0 = (const float*)d_in[7];
  const float* Wout1 = (const float*)d_in[8];
  const float* bout1 = (const float*)d_in[9];
  u16*   ws  = (u16*)d_ws;
  float* out = (float*)d_out;

  pack_kernel   <<<4096, 256, 0, stream>>>(x0, x1, ws);
  wconv_kernel  <<<4096, 256, 0, stream>>>(Wkv0, Wkv1, ws);
  qproj_kernel  <<<dim3(32,4,16), 256, 0, stream>>>(x0, x1, Wq0, Wq1, ws);
  kvproj_kernel <<<dim3(8,8,16),  256, 0, stream>>>(ws);
  attn_kernel   <<<dim3(64,8,16), 256, 0, stream>>>(ws);
  outproj_kernel<<<dim3(32,2,8),  256, 0, stream>>>(x0, x1, Wout0, Wout1,
                                                    bout0, bout1, ws, out);
}

// Round 4
// 549.235 us; speedup vs baseline: 1.3532x; 1.3291x over previous
//
#include <hip/hip_runtime.h>
#include <hip/hip_bf16.h>

// ============================================================================
// SphCrossAttFusionBlock: B=8, DIM=256, Y=4096, H=8, D=64, INNER=512, w=256
// fp32 I/O; bf16 internal (ws) with fp32 MFMA accumulation.
// Pipeline: pack -> wconv -> qproj -> kvproj(K-split) -> kvreduce -> attn -> outproj
// ws layout (u16 elems):
//   xpT[s]: s*8388608                 [b][w=256][k=4096] (k = n*16+p*4+q)
//   q[s]:   16777216 + s*16777216     [b][o=512][y=4096] (o = h*64+d)
//   att[s]: 50331648 + s*16777216     [b][y=4096][c=512] (c = h*64+d)
//     att0 head doubles as wkv_bf[2][1024][4096] (wconv -> kvproj, dead after).
//     att1 region doubles as fp32 partials part[2s][2kh][1024][2048] (kvproj ->
//     kvreduce, dead after; attn overwrites both att regions later).
//   k[s]:   83886080 + s*1048576      [b][h][j=256][d=64]
//   v[s]:   85983232 + s*1048576      [b][h][d=64][j=256]  (transposed)
// total 88080384 u16 = 176,160,768 bytes of d_ws
// ============================================================================

typedef unsigned short u16;
typedef unsigned int   u32;
typedef __bf16 v8bf __attribute__((ext_vector_type(8)));
typedef float  v4f  __attribute__((ext_vector_type(4)));
typedef u16    v8u  __attribute__((ext_vector_type(8)));

#define MFMA16(a,b,c) __builtin_amdgcn_mfma_f32_16x16x32_bf16((a),(b),(c),0,0,0)

__device__ __forceinline__ u16 f2bf(float f){ union{float f; u32 i;} x; x.f=f; u32 r=x.i+0x7FFFu+((x.i>>16)&1u); return (u16)(r>>16); }

__device__ __forceinline__ v8bf load8f_bf(const float* __restrict__ p){
  union { v8bf v; u16 u[8]; } t;
  float4 a = *(const float4*)p, b = *(const float4*)(p+4);
  t.u[0]=f2bf(a.x); t.u[1]=f2bf(a.y); t.u[2]=f2bf(a.z); t.u[3]=f2bf(a.w);
  t.u[4]=f2bf(b.x); t.u[5]=f2bf(b.y); t.u[6]=f2bf(b.z); t.u[7]=f2bf(b.w);
  return t.v;
}

// async global->LDS, 16B per lane; LDS dest must be linear (base + lane*16)
__device__ __forceinline__ void gld16(u16* lds, const u16* g) {
  __builtin_amdgcn_global_load_lds(
      (const __attribute__((address_space(1))) void*)g,
      (__attribute__((address_space(3))) void*)lds, 16, 0, 0);
}

#define OFF_XPT(s) ((size_t)(s)*8388608u)
#define OFF_Q(s)   ((size_t)16777216u + (size_t)(s)*16777216u)
#define OFF_ATT(s) ((size_t)50331648u + (size_t)(s)*16777216u)
#define OFF_WKV(s) ((size_t)50331648u + (size_t)(s)*4194304u)   // aliases att0 head
#define OFF_K(s)   ((size_t)83886080u + (size_t)(s)*1048576u)
#define OFF_V(s)   ((size_t)85983232u + (size_t)(s)*1048576u)

// ---------------------------------------------------------------------------
// pack: xpT[s][b][w][n*16+j] = bf16(x_s[b][n][w*16+j])
// ---------------------------------------------------------------------------
__global__ __launch_bounds__(256) void pack_kernel(const float* __restrict__ x0,
    const float* __restrict__ x1, u16* __restrict__ ws) {
  const int w = blockIdx.x & 255;
  const int b = (blockIdx.x >> 8) & 7;
  const int s = blockIdx.x >> 11;
  const float* x = s ? x1 : x0;
  const int n = threadIdx.x;
  const float* src = x + ((size_t)(b*256 + n))*4096 + w*16;
  u16* dst = ws + OFF_XPT(s) + ((size_t)(b*256 + w))*4096 + n*16;
  float4 f0 = *(const float4*)(src);
  float4 f1 = *(const float4*)(src+4);
  float4 f2 = *(const float4*)(src+8);
  float4 f3 = *(const float4*)(src+12);
  union { v8u v; u16 u[8]; } lo, hi;
  lo.u[0]=f2bf(f0.x); lo.u[1]=f2bf(f0.y); lo.u[2]=f2bf(f0.z); lo.u[3]=f2bf(f0.w);
  lo.u[4]=f2bf(f1.x); lo.u[5]=f2bf(f1.y); lo.u[6]=f2bf(f1.z); lo.u[7]=f2bf(f1.w);
  hi.u[0]=f2bf(f2.x); hi.u[1]=f2bf(f2.y); hi.u[2]=f2bf(f2.z); hi.u[3]=f2bf(f2.w);
  hi.u[4]=f2bf(f3.x); hi.u[5]=f2bf(f3.y); hi.u[6]=f2bf(f3.z); hi.u[7]=f2bf(f3.w);
  *(v8u*)(dst)   = lo.v;
  *(v8u*)(dst+8) = hi.v;
}

// ---------------------------------------------------------------------------
// wconv: wkv_bf[s][o][k] = bf16(Wkv_s[o][k])
// ---------------------------------------------------------------------------
__global__ __launch_bounds__(256) void wconv_kernel(const float* __restrict__ Wkv0,
    const float* __restrict__ Wkv1, u16* __restrict__ ws) {
  int tid = blockIdx.x*256 + threadIdx.x;
  int s = tid >> 19;
  int i8 = tid & 524287;
  const float* W = s ? Wkv1 : Wkv0;
  const float* src = W + (size_t)i8*8;
  u16* dst = ws + OFF_WKV(s) + (size_t)i8*8;
  float4 a = *(const float4*)src, b = *(const float4*)(src+4);
  union { v8u v; u16 u[8]; } t;
  t.u[0]=f2bf(a.x); t.u[1]=f2bf(a.y); t.u[2]=f2bf(a.z); t.u[3]=f2bf(a.w);
  t.u[4]=f2bf(b.x); t.u[5]=f2bf(b.y); t.u[6]=f2bf(b.z); t.u[7]=f2bf(b.w);
  *(v8u*)dst = t.v;
}

// ---------------------------------------------------------------------------
// qproj: per (s,b): C[512,4096] = Wq[512,256] x x_b[256,4096] -> q[b][o][y]
// ---------------------------------------------------------------------------
__global__ __launch_bounds__(256) void qproj_kernel(const float* __restrict__ x0,
    const float* __restrict__ x1, const float* __restrict__ Wq0,
    const float* __restrict__ Wq1, u16* __restrict__ ws) {
  const int yt = blockIdx.x;            // 0..31
  const int ot = blockIdx.y;            // 0..3
  const int s  = blockIdx.z >> 3, b = blockIdx.z & 7;
  const float* x  = s ? x1 : x0;
  const float* Wq = s ? Wq1 : Wq0;
  u16* qout = ws + OFF_Q(s);
  const int y0 = yt*128, o0 = ot*128;

  __shared__ u16 sm[32768];             // xT panel [128 y][256 n] swizzled (64KB)
  {
    const int tn = threadIdx.x >> 4;          // 0..15
    const int ty = (threadIdx.x & 15) * 8;    // 0..120 (ty&7==0)
    #pragma unroll
    for (int pass = 0; pass < 16; ++pass) {
      int n = pass*16 + tn;
      const float* src = x + ((size_t)(b*256 + n))*4096 + y0 + ty;
      float4 fa = *(const float4*)src, fb = *(const float4*)(src+4);
      u16 vals[8] = { f2bf(fa.x), f2bf(fa.y), f2bf(fa.z), f2bf(fa.w),
                      f2bf(fb.x), f2bf(fb.y), f2bf(fb.z), f2bf(fb.w) };
      #pragma unroll
      for (int j = 0; j < 8; ++j) {
        int row = ty + j;                     // row&7 == j
        int byte = row*512 + ((2*n) ^ (j<<4));
        sm[byte>>1] = vals[j];
      }
    }
  }
  __syncthreads();

  const int lane = threadIdx.x & 63, wv = threadIdx.x >> 6;
  const int l16 = lane & 15, g = lane >> 4;
  const int wm = wv >> 1, wn = wv & 1;

  v4f acc[4][4] = {};
  #pragma unroll
  for (int ks = 0; ks < 8; ++ks) {
    v8bf a[4], bb[4];
    #pragma unroll
    for (int mt = 0; mt < 4; ++mt)
      a[mt] = load8f_bf(Wq + (size_t)(o0 + wm*64 + mt*16 + l16)*256 + ks*32 + g*8);
    #pragma unroll
    for (int nt = 0; nt < 4; ++nt) {
      int row = wn*64 + nt*16 + l16;
      int c = ks*4 + g;
      int byte = row*512 + ((c*16) ^ ((row&7)<<4));
      bb[nt] = *(const v8bf*)&sm[byte>>1];
    }
    #pragma unroll
    for (int mt = 0; mt < 4; ++mt)
      #pragma unroll
      for (int nt = 0; nt < 4; ++nt)
        acc[mt][nt] = MFMA16(a[mt], bb[nt], acc[mt][nt]);
  }
  #pragma unroll
  for (int mt = 0; mt < 4; ++mt)
    #pragma unroll
    for (int nt = 0; nt < 4; ++nt)
      #pragma unroll
      for (int r = 0; r < 4; ++r) {
        int o = o0 + wm*64 + mt*16 + g*4 + r;
        int y = y0 + wn*64 + nt*16 + l16;
        qout[(size_t)(b*512 + o)*4096 + y] = f2bf(acc[mt][nt][r]);
      }
}

// ---------------------------------------------------------------------------
// kvproj v3 (m97 structure, K-split): per (s,kh):
//   part[s][kh][1024][2048] += wkv_bf[s][:, kh*2048 + 0..2048) x xpT[s]^T
// 128x128 tile, BK=64, global_load_lds w16 with pre-swizzled source,
// swizzled ds_read_b128, 4 waves (2x2), 4x4 frags/wave, fp32 partial out.
// ---------------------------------------------------------------------------
__global__ __launch_bounds__(256) void kvproj_kernel(const u16* __restrict__ ws,
                                                     float* __restrict__ part) {
  const int mt8 = blockIdx.x;           // 0..7   (XCD = bid%8 = M-tile)
  const int nt  = blockIdx.y;           // 0..15
  const int z   = blockIdx.z;           // 0..3: s = z>>1, kh = z&1
  const int s = z >> 1, kh = z & 1;
  const u16* A = ws + OFF_WKV(s);       // [1024][4096]
  const u16* Bm = ws + OFF_XPT(s);      // [2048][4096]  (rows = b*256+w)
  const int m0 = mt8*128, n0 = nt*128, kbase = kh*2048;

  __shared__ u16 smA[8192];             // [128][64] linear, source-swizzled
  __shared__ u16 smB[8192];

  const int t = threadIdx.x;
  const int trow = t >> 3, tu = t & 7;
  const int cswz = ((tu ^ (trow & 7)) * 8);
  const u16* Asrc = A  + (size_t)(m0 + trow)*4096 + kbase + cswz;
  const u16* Bsrc = Bm + (size_t)(n0 + trow)*4096 + kbase + cswz;
  u16* Adst = smA + t*8;
  u16* Bdst = smB + t*8;

  const int lane = t & 63, wv = t >> 6;
  const int l16 = lane & 15, g = lane >> 4;
  const int wm = wv >> 1, wn = wv & 1;
  const int swz = l16 & 7;

  v4f acc[4][4] = {};
  for (int k0 = 0; k0 < 2048; k0 += 64) {
    #pragma unroll
    for (int i = 0; i < 4; ++i) {
      gld16(Adst + i*2048, Asrc + k0 + (size_t)i*32*4096);
      gld16(Bdst + i*2048, Bsrc + k0 + (size_t)i*32*4096);
    }
    __syncthreads();
    #pragma unroll
    for (int ks = 0; ks < 2; ++ks) {
      v8bf a[4], bb[4];
      #pragma unroll
      for (int mt = 0; mt < 4; ++mt) {
        int row = wm*64 + mt*16 + l16;
        a[mt] = *(const v8bf*)&smA[row*64 + (((ks*4+g) ^ swz)<<3)];
      }
      #pragma unroll
      for (int ntf = 0; ntf < 4; ++ntf) {
        int row = wn*64 + ntf*16 + l16;
        bb[ntf] = *(const v8bf*)&smB[row*64 + (((ks*4+g) ^ swz)<<3)];
      }
      #pragma unroll
      for (int mt = 0; mt < 4; ++mt)
        #pragma unroll
        for (int ntf = 0; ntf < 4; ++ntf)
          acc[mt][ntf] = MFMA16(a[mt], bb[ntf], acc[mt][ntf]);
    }
    __syncthreads();
  }

  float* p = part + ((size_t)z*1024 + m0)*2048 + n0;
  #pragma unroll
  for (int mt = 0; mt < 4; ++mt)
    #pragma unroll
    for (int ntf = 0; ntf < 4; ++ntf)
      #pragma unroll
      for (int r = 0; r < 4; ++r) {
        int row = wm*64 + mt*16 + g*4 + r;
        int col = wn*64 + ntf*16 + l16;
        p[(size_t)row*2048 + col] = acc[mt][ntf][r];
      }
}

// ---------------------------------------------------------------------------
// kvreduce: sum K-halves, bf16, scatter to k[b][h][j][d] / v[b][h][d][w]
// ---------------------------------------------------------------------------
__global__ __launch_bounds__(256) void kvreduce_kernel(const float* __restrict__ part,
                                                       u16* __restrict__ ws) {
  int tid = blockIdx.x*256 + threadIdx.x;   // 524288 threads
  int n8 = tid & 255;                       // n = n8*8
  int o  = (tid >> 8) & 1023;
  int s  = tid >> 18;
  const float* p0 = part + (((size_t)(s*2+0)*1024 + o)*2048) + n8*8;
  const float* p1 = part + (((size_t)(s*2+1)*1024 + o)*2048) + n8*8;
  float4 a0 = *(const float4*)p0, a1 = *(const float4*)(p0+4);
  float4 b0 = *(const float4*)p1, b1 = *(const float4*)(p1+4);
  float v0 = a0.x+b0.x, v1 = a0.y+b0.y, v2 = a0.z+b0.z, v3 = a0.w+b0.w;
  float v4 = a1.x+b1.x, v5 = a1.y+b1.y, v6 = a1.z+b1.z, v7 = a1.w+b1.w;
  int n = n8*8;
  int b = n >> 8, w0 = n & 255;
  if (o < 512) {
    int hh = o >> 6, d = o & 63;
    u16* kout = ws + OFF_K(s) + ((size_t)(b*8+hh)*256)*64 + d;
    kout[(w0+0)*64] = f2bf(v0); kout[(w0+1)*64] = f2bf(v1);
    kout[(w0+2)*64] = f2bf(v2); kout[(w0+3)*64] = f2bf(v3);
    kout[(w0+4)*64] = f2bf(v4); kout[(w0+5)*64] = f2bf(v5);
    kout[(w0+6)*64] = f2bf(v6); kout[(w0+7)*64] = f2bf(v7);
  } else {
    int oo = o - 512, hh = oo >> 6, d = oo & 63;
    union { v8u v; u16 u[8]; } t;
    t.u[0]=f2bf(v0); t.u[1]=f2bf(v1); t.u[2]=f2bf(v2); t.u[3]=f2bf(v3);
    t.u[4]=f2bf(v4); t.u[5]=f2bf(v5); t.u[6]=f2bf(v6); t.u[7]=f2bf(v7);
    *(v8u*)(ws + OFF_V(s) + ((size_t)(b*8+hh)*64 + d)*256 + w0) = t.v;
  }
}

// ---------------------------------------------------------------------------
// attn: per (s,b,h,itile): 64 q-rows (16/wave). Stream s uses q_s, k/v_{1-s}.
// ---------------------------------------------------------------------------
__global__ __launch_bounds__(256) void attn_kernel(u16* __restrict__ ws) {
  const int it = blockIdx.x;            // 0..63
  const int hh = blockIdx.y;            // 0..7
  const int s  = blockIdx.z >> 3, b = blockIdx.z & 7;
  const u16* q  = ws + OFF_Q(s);
  const u16* kk = ws + OFF_K(1-s);
  const u16* vv = ws + OFF_V(1-s);
  u16* att = ws + OFF_ATT(s);

  __shared__ u16 sm[32768];             // 64KB
  const int lane = threadIdx.x & 63, wv = threadIdx.x >> 6;
  const int l16 = lane & 15, g = lane >> 4;

  const u16* kbase = kk + (size_t)(b*8+hh)*16384;
  #pragma unroll
  for (int pass = 0; pass < 8; ++pass) {
    int byte = pass*4096 + threadIdx.x*16;
    int row = byte >> 7, u = (byte >> 4) & 7;
    v8u val = *(const v8u*)(kbase + row*64 + u*8);
    int db = row*128 + ((u*16) ^ ((row&7)<<4));
    *(v8u*)&sm[db>>1] = val;
  }
  const u16* vbase = vv + (size_t)(b*8+hh)*16384;
  #pragma unroll
  for (int pass = 0; pass < 8; ++pass) {
    int byte = pass*4096 + threadIdx.x*16;
    int row = byte >> 9, u = (byte >> 4) & 31;
    v8u val = *(const v8u*)(vbase + row*256 + u*8);
    int db = 32768 + row*512 + ((u*16) ^ ((row&7)<<4));
    *(v8u*)&sm[db>>1] = val;
  }
  __syncthreads();

  const int i0 = it*64 + wv*16;
  v8bf aq[2];
  {
    union { v8bf v; u16 u[8]; } tmp;
    #pragma unroll
    for (int half = 0; half < 2; ++half) {
      #pragma unroll
      for (int jj = 0; jj < 8; ++jj) {
        int d = half*32 + g*8 + jj;
        tmp.u[jj] = q[((size_t)(b*512) + hh*64 + d)*4096 + i0 + l16];
      }
      aq[half] = tmp.v;
    }
  }
  v4f sfr[16];
  #pragma unroll
  for (int t = 0; t < 16; ++t) {
    v4f acc = {};
    #pragma unroll
    for (int half = 0; half < 2; ++half) {
      int row = t*16 + l16;
      int c = half*4 + g;
      int byte = row*128 + ((c*16) ^ ((row&7)<<4));
      v8bf bk = *(const v8bf*)&sm[byte>>1];
      acc = MFMA16(aq[half], bk, acc);
    }
    sfr[t] = acc;
  }
  float inv4[4];
  #pragma unroll
  for (int r = 0; r < 4; ++r) {
    float m = -3.0e38f;
    #pragma unroll
    for (int t = 0; t < 16; ++t) m = fmaxf(m, sfr[t][r]);
    #pragma unroll
    for (int off = 1; off < 16; off <<= 1) m = fmaxf(m, __shfl_xor(m, off));
    float sum = 0.f;
    #pragma unroll
    for (int t = 0; t < 16; ++t) {
      float p = exp2f((sfr[t][r] - m) * 0.18033688011112042f);  // (1/8)*log2(e)
      sfr[t][r] = p;
      sum += p;
    }
    #pragma unroll
    for (int off = 1; off < 16; off <<= 1) sum += __shfl_xor(sum, off);
    inv4[r] = 1.0f / sum;
  }
  __syncthreads();
  const int pbase = wv*8192;
  #pragma unroll
  for (int t = 0; t < 16; ++t)
    #pragma unroll
    for (int r = 0; r < 4; ++r) {
      int irow = g*4 + r;
      int j = t*16 + l16;
      int byte = pbase + irow*512 + ((2*j) ^ ((irow&7)<<4));
      sm[byte>>1] = f2bf(sfr[t][r] * inv4[r]);
    }
  __syncthreads();
  v4f oacc[4] = {};
  #pragma unroll
  for (int ksj = 0; ksj < 8; ++ksj) {
    int cp = ksj*4 + g;
    int pbyte = pbase + l16*512 + ((cp*16) ^ ((l16&7)<<4));
    v8bf pa = *(const v8bf*)&sm[pbyte>>1];
    #pragma unroll
    for (int dt = 0; dt < 4; ++dt) {
      int rowv = dt*16 + l16;
      int byte = 32768 + rowv*512 + ((cp*16) ^ ((rowv&7)<<4));
      v8bf vb = *(const v8bf*)&sm[byte>>1];
      oacc[dt] = MFMA16(pa, vb, oacc[dt]);
    }
  }
  #pragma unroll
  for (int dt = 0; dt < 4; ++dt)
    #pragma unroll
    for (int r = 0; r < 4; ++r) {
      int i = i0 + g*4 + r;
      int c = hh*64 + dt*16 + l16;
      att[((size_t)(b*4096) + i)*512 + c] = f2bf(oacc[dt][r]);
    }
}

// ---------------------------------------------------------------------------
// outproj: out = 0.5*(x0+x1 + b0[o]+b1[o] + Wout0@att0 + Wout1@att1)  (fp32)
// ---------------------------------------------------------------------------
__global__ __launch_bounds__(256) void outproj_kernel(const float* __restrict__ x0,
    const float* __restrict__ x1, const float* __restrict__ Wout0,
    const float* __restrict__ Wout1, const float* __restrict__ bout0,
    const float* __restrict__ bout1, const u16* __restrict__ ws,
    float* __restrict__ out) {
  const int yt = blockIdx.x;            // 0..31
  const int ot = blockIdx.y;            // 0..1
  const int b  = blockIdx.z;            // 0..7
  const int lane = threadIdx.x & 63, wv = threadIdx.x >> 6;
  const int l16 = lane & 15, g = lane >> 4;
  const int wm = wv >> 1, wn = wv & 1;
  const int y0 = yt*128, o0 = ot*128;

  v4f acc[4][4] = {};
  #pragma unroll
  for (int s = 0; s < 2; ++s) {
    const float* Wout = s ? Wout1 : Wout0;
    const u16* att = ws + OFF_ATT(s);
    #pragma unroll
    for (int ks = 0; ks < 16; ++ks) {
      v8bf a[4], bb[4];
      #pragma unroll
      for (int mt = 0; mt < 4; ++mt)
        a[mt] = load8f_bf(Wout + (size_t)(o0 + wm*64 + mt*16 + l16)*512 + ks*32 + g*8);
      #pragma unroll
      for (int nt = 0; nt < 4; ++nt)
        bb[nt] = *(const v8bf*)(att + ((size_t)(b*4096) + y0 + wn*64 + nt*16 + l16)*512 + ks*32 + g*8);
      #pragma unroll
      for (int mt = 0; mt < 4; ++mt)
        #pragma unroll
        for (int nt = 0; nt < 4; ++nt)
          acc[mt][nt] = MFMA16(a[mt], bb[nt], acc[mt][nt]);
    }
  }
  #pragma unroll
  for (int mt = 0; mt < 4; ++mt)
    #pragma unroll
    for (int nt = 0; nt < 4; ++nt)
      #pragma unroll
      for (int r = 0; r < 4; ++r) {
        int o = o0 + wm*64 + mt*16 + g*4 + r;
        int y = y0 + wn*64 + nt*16 + l16;
        size_t idx = (size_t)(b*256 + o)*4096 + y;
        float bias = bout0[o] + bout1[o];
        out[idx] = 0.5f*(acc[mt][nt][r] + bias + x0[idx] + x1[idx]);
      }
}

// ---------------------------------------------------------------------------
extern "C" void kernel_launch(void* const* d_in, const int* in_sizes, int n_in,
                              void* d_out, int out_size, void* d_ws, size_t ws_size,
                              hipStream_t stream) {
  const float* x0    = (const float*)d_in[0];
  const float* x1    = (const float*)d_in[1];
  const float* Wq0   = (const float*)d_in[2];
  const float* Wkv0  = (const float*)d_in[3];
  const float* Wq1   = (const float*)d_in[4];
  const float* Wkv1  = (const float*)d_in[5];
  const float* Wout0 = (const float*)d_in[6];
  const float* bout0 = (const float*)d_in[7];
  const float* Wout1 = (const float*)d_in[8];
  const float* bout1 = (const float*)d_in[9];
  u16*   ws   = (u16*)d_ws;
  float* part = (float*)(ws + OFF_ATT(1));   // 32MB fp32 partials in att1
  float* out  = (float*)d_out;

  pack_kernel    <<<4096, 256, 0, stream>>>(x0, x1, ws);
  wconv_kernel   <<<4096, 256, 0, stream>>>(Wkv0, Wkv1, ws);
  qproj_kernel   <<<dim3(32,4,16), 256, 0, stream>>>(x0, x1, Wq0, Wq1, ws);
  kvproj_kernel  <<<dim3(8,16,4),  256, 0, stream>>>(ws, part);
  kvreduce_kernel<<<2048, 256, 0, stream>>>(part, ws);
  attn_kernel    <<<dim3(64,8,16), 256, 0, stream>>>(ws);
  outproj_kernel <<<dim3(32,2,8),  256, 0, stream>>>(x0, x1, Wout0, Wout1,
                                                     bout0, bout1, ws, out);
}